// Round 2
// baseline (368.221 us; speedup 1.0000x reference)
//
#include <hip/hip_runtime.h>
#include <hip/hip_cooperative_groups.h>
#include <math.h>

namespace cg = cooperative_groups;

#define M_ 3
#define B_ 64
#define D_ 512
#define H4 128     // D/4
#define HIST_ 5
#define BD (B_ * D_)        // 32768
#define INVSCALE 0.04419417382415922f   // 1/sqrt(512)
#define LOG2E 1.4426950408889634f
#define GRID 512

__device__ __forceinline__ float wave_sum64(float v) {
#pragma unroll
    for (int o = 32; o >= 1; o >>= 1) v += __shfl_xor(v, o, 64);
    return v;
}

__device__ __forceinline__ float sigmoidf(float x) {
    return 1.0f / (1.0f + __expf(-x));
}

// ===========================================================================
// R8: single cooperative kernel, 4 phases separated by grid.sync().
// Work decompositions identical to R7; lnmlp re-mapped to 256 threads
// (each thread owns d = t and d = t+256).
// LDS: one 8.5KB overlay buffer reused per phase (2 blocks/CU -> 17KB/CU).
// ===========================================================================
__global__ __launch_bounds__(256, 2) void k_fused(
    const float* __restrict__ x, const float* __restrict__ pW,
    const float* __restrict__ pb, const float* __restrict__ lg,
    const float* __restrict__ lb, const float* __restrict__ W1,
    const float* __restrict__ b1, const float* __restrict__ W2,
    const float* __restrict__ b2, const float* __restrict__ gamma,
    const float* __restrict__ mbias, const float* __restrict__ cons,
    float* __restrict__ wf, float* __restrict__ Ssum,
    float* __restrict__ HT, float* __restrict__ ypart,
    float* __restrict__ out)
{
    cg::grid_group grid = cg::this_grid();
    const int t   = threadIdx.x;
    const int bid = blockIdx.x;
    __shared__ __align__(16) float smem[2176];   // 8.5 KB overlay

    // ---------------- P1: proj partial GEMM + out zero + attn weights ------
    if (bid < 128)
        out[(bid << 8) + t] = 0.f;

    for (int w = bid; w < 768; w += GRID) {
        const int m    = w >> 8;
        const int r    = w & 255;
        const int kq   = r >> 6;
        const int rem2 = r & 63;
        const int dh   = rem2 >> 5;
        const int b0   = (rem2 & 31) << 1;
        const int d    = (dh << 8) + t;

        float4* xs = (float4*)smem;              // [64] float4 (2 rows x 32)
        if (t < 64)
            xs[t] = ((const float4*)(x + (size_t)(m * B_ + b0 + (t >> 5)) * D_ + kq * 128))[t & 31];
        __syncthreads();

        const float4* wr = (const float4*)(pW + (size_t)m * D_ * D_ + (size_t)d * D_ + kq * 128);
        float acc0 = 0.f, acc1 = 0.f;
#pragma unroll
        for (int k = 0; k < 32; ++k) {
            const float4 wv4 = wr[k];
            const float4 a = xs[k];
            const float4 b = xs[32 + k];
            acc0 = fmaf(wv4.x, a.x, acc0); acc0 = fmaf(wv4.y, a.y, acc0);
            acc0 = fmaf(wv4.z, a.z, acc0); acc0 = fmaf(wv4.w, a.w, acc0);
            acc1 = fmaf(wv4.x, b.x, acc1); acc1 = fmaf(wv4.y, b.y, acc1);
            acc1 = fmaf(wv4.z, b.z, acc1); acc1 = fmaf(wv4.w, b.w, acc1);
        }
        const size_t idx0 = (size_t)(m * B_ + b0) * 2048 + kq * 512 + d;
        ypart[idx0]        = acc0;
        ypart[idx0 + 2048] = acc1;
        __syncthreads();                          // protect xs reuse
    }

    if (bid == 0 && t == 0) {
        const float g01 = sigmoidf(gamma[1]), g02 = sigmoidf(gamma[2]);
        const float g10 = sigmoidf(gamma[3]), g12 = sigmoidf(gamma[5]);
        const float g20 = sigmoidf(gamma[6]), g21 = sigmoidf(gamma[7]);
        const float s0 = 0.5f * (g01 + g02);
        const float s1 = 0.5f * (g10 + g12);
        const float s2 = 0.5f * (g20 + g21);
        const float mx = fmaxf(s0, fmaxf(s1, s2));
        const float e0 = __expf(s0 - mx), e1 = __expf(s1 - mx), e2 = __expf(s2 - mx);
        const float den = e0 + e1 + e2;
        out[BD + 0] = e0 / den;
        out[BD + 1] = e1 / den;
        out[BD + 2] = e2 / den;
    }

    grid.sync();

    // ---------------- P2: LN + MLP + wf + Ssum (blocks 0..191) -------------
    if (bid < 192) {
        const int m = bid >> 6;
        const int b = bid & 63;
        float* ps    = smem;          // [512]
        float* hpart = smem + 512;    // [256]
        float* hs    = smem + 768;    // [128]
        float* red   = smem + 896;    // [4]

        const size_t rbase = (size_t)(m * B_ + b) * 2048;
        const float y0 = ypart[rbase + t]        + ypart[rbase + 512 + t]
                       + ypart[rbase + 1024 + t] + ypart[rbase + 1536 + t]
                       + pb[m * D_ + t];
        const float y1 = ypart[rbase + t + 256]        + ypart[rbase + 512 + t + 256]
                       + ypart[rbase + 1024 + t + 256] + ypart[rbase + 1536 + t + 256]
                       + pb[m * D_ + t + 256];

        float s = wave_sum64(y0 + y1);
        if ((t & 63) == 0) red[t >> 6] = s;
        __syncthreads();
        const float mean = (red[0] + red[1] + red[2] + red[3]) * (1.f / D_);
        __syncthreads();
        const float v0 = y0 - mean, v1 = y1 - mean;
        float vs = wave_sum64(v0 * v0 + v1 * v1);
        if ((t & 63) == 0) red[t >> 6] = vs;
        __syncthreads();
        const float inv = rsqrtf((red[0] + red[1] + red[2] + red[3]) * (1.f / D_) + 1e-5f);
        const float p0 = fmaxf(fmaf(v0 * inv, lg[m * D_ + t],       lb[m * D_ + t]),       0.f);
        const float p1 = fmaxf(fmaf(v1 * inv, lg[m * D_ + t + 256], lb[m * D_ + t + 256]), 0.f);
        ps[t]       = p0;
        ps[t + 256] = p1;
        __syncthreads();

        // MLP1: r = t&127, seg = t>>7 -> 256-length dot each
        {
            const int r = t & 127, seg = t >> 7;
            const float4* w1 = (const float4*)(W1 + ((size_t)m * H4 + r) * D_) + (seg << 6);
            const float4* pv = (const float4*)ps + (seg << 6);
            float a1 = 0.f;
#pragma unroll
            for (int k = 0; k < 64; ++k) {
                const float4 wq = w1[k], pp = pv[k];
                a1 = fmaf(wq.x, pp.x, a1); a1 = fmaf(wq.y, pp.y, a1);
                a1 = fmaf(wq.z, pp.z, a1); a1 = fmaf(wq.w, pp.w, a1);
            }
            hpart[t] = a1;
        }
        __syncthreads();
        if (t < H4)
            hs[t] = fmaxf(hpart[t] + hpart[t + 128] + b1[m * H4 + t], 0.f);
        __syncthreads();

        // MLP2: two outputs per thread (d = t, t+256), shared hh loads
        const float4* w2a = (const float4*)(W2 + ((size_t)m * D_ + t) * H4);
        const float4* w2b = (const float4*)(W2 + ((size_t)m * D_ + t + 256) * H4);
        const float4* hv  = (const float4*)hs;
        float a2_0 = 0.f, a2_1 = 0.f;
#pragma unroll
        for (int k = 0; k < H4 / 4; ++k) {
            const float4 hh4 = hv[k];
            const float4 wA = w2a[k], wB = w2b[k];
            a2_0 = fmaf(wA.x, hh4.x, a2_0); a2_0 = fmaf(wA.y, hh4.y, a2_0);
            a2_0 = fmaf(wA.z, hh4.z, a2_0); a2_0 = fmaf(wA.w, hh4.w, a2_0);
            a2_1 = fmaf(wB.x, hh4.x, a2_1); a2_1 = fmaf(wB.y, hh4.y, a2_1);
            a2_1 = fmaf(wB.z, hh4.z, a2_1); a2_1 = fmaf(wB.w, hh4.w, a2_1);
        }
        const float wv0 = p0 * sigmoidf(a2_0 + b2[m * D_ + t]);
        const float wv1 = p1 * sigmoidf(a2_1 + b2[m * D_ + t + 256]);
        wf[(size_t)(m * B_ + b) * D_ + t]       = wv0;
        wf[(size_t)(m * B_ + b) * D_ + t + 256] = wv1;
        atomicAdd(&out[b * D_ + t],       wv0 * (1.f / 3.f));
        atomicAdd(&out[b * D_ + t + 256], wv1 * (1.f / 3.f));

        float tot = wave_sum64(wv0 + wv1);
        if ((t & 63) == 0) red[t >> 6] = tot;
        __syncthreads();
        if (t == 0)
            Ssum[m * B_ + b] = red[0] + red[1] + red[2] + red[3];
    }

    grid.sync();

    // ---------------- P3: fuse pass A (items 0..767) + history (768..1151) -
    for (int w = bid; w < 1152; w += GRID) {
        if (w < 768) {
            const int i    = w >> 8;
            const int rem  = w & 255;
            const int b0   = (rem >> 4) << 2;
            const int dc   = rem & 15;
            const int ln   = t & 31;
            const int d    = (dc << 5) + ln;
            const int esec = t >> 5;
            const int jA   = (i == 0) ? 1 : 0;

            const float c08 = cons[i] * (0.8f * LOG2E);
            float a08[4], a02[4];
            const float* uAp[4];
#pragma unroll
            for (int bb = 0; bb < 4; ++bb) {
                const float a = wf[(size_t)i * BD + (b0 + bb) * D_ + d];
                a08[bb] = a * (0.8f * INVSCALE * LOG2E);
                a02[bb] = a * (0.2f * INVSCALE * LOG2E);
                uAp[bb] = wf + (size_t)jA * BD + (b0 + bb) * D_ + (esec << 6);
            }

            float sA[4] = {0.f, 0.f, 0.f, 0.f};
            float dA[4] = {0.f, 0.f, 0.f, 0.f};
#pragma unroll 2
            for (int e = 0; e < 64; e += 4) {
#pragma unroll
                for (int bb = 0; bb < 4; ++bb) {
                    const float4 u4 = *(const float4*)(uAp[bb] + e);
                    const float uu[4] = {u4.x, u4.y, u4.z, u4.w};
#pragma unroll
                    for (int k = 0; k < 4; ++k) {
                        const float v1 = a08[bb] * uu[k];
                        const float v2 = fminf(v1, c08);
                        const float f  = fmaf(a02[bb], uu[k], v2);
                        const float p  = __builtin_amdgcn_exp2f(f);
                        sA[bb] += p;
                        dA[bb] = fmaf(p, uu[k], dA[bb]);
                    }
                }
            }

            float2* part = (float2*)smem;        // [4][256]
#pragma unroll
            for (int bb = 0; bb < 4; ++bb)
                part[bb * 256 + t] = make_float2(sA[bb], dA[bb]);
            __syncthreads();
            if (t < 128) {
                const int bb = t >> 5;
                const int l  = t & 31;
                float Ss = 0.f, Sd = 0.f;
#pragma unroll
                for (int k = 0; k < 8; ++k) {
                    const float2 pp = part[bb * 256 + l + (k << 5)];
                    Ss += pp.x; Sd += pp.y;
                }
                const float gA = sigmoidf(gamma[i * 3 + jA]);
                const float pv = gA * (Sd / Ss + mbias[i * 3 + jA] * Ssum[jA * B_ + b0 + bb]);
                atomicAdd(&out[(b0 + bb) * D_ + (dc << 5) + l], pv * (1.f / 6.f));
            }
            __syncthreads();                      // protect part reuse
        } else {
            const int hw = w - 768;
            const int i  = hw >> 7;
            const int e0 = (hw & 127) << 2;
            const int j  = (i == 0) ? 1 : 0;
            const float c = cons[i];
            const float* wfi = wf + (size_t)i * BD;
            const float* wfj = wf + (size_t)j * BD;

            float h0[4] = {0.f, 0.f, 0.f, 0.f};
            float h1[4] = {0.f, 0.f, 0.f, 0.f};
#pragma unroll 2
            for (int b = 0; b < B_; ++b) {
                const float a0 = wfi[b * D_ + t]       * INVSCALE;
                const float a1 = wfi[b * D_ + t + 256] * INVSCALE;
                const float4 u4 = *(const float4*)(wfj + b * D_ + e0);
                const float uu[4] = {u4.x, u4.y, u4.z, u4.w};
#pragma unroll
                for (int k = 0; k < 4; ++k) {
                    float tt = a0 * uu[k]; float mm = fminf(tt, c);
                    h0[k] = fmaf(0.8f, mm, fmaf(0.2f, tt, h0[k]));
                    tt = a1 * uu[k]; mm = fminf(tt, c);
                    h1[k] = fmaf(0.8f, mm, fmaf(0.2f, tt, h1[k]));
                }
            }
            const float hsc = LOG2E / (float)(B_ * HIST_);
            float* r0 = HT + ((size_t)(i << 9) + e0) * D_;
#pragma unroll
            for (int k = 0; k < 4; ++k) {
                r0[(size_t)k * D_ + t]       = h0[k] * hsc;
                r0[(size_t)k * D_ + t + 256] = h1[k] * hsc;
            }
        }
    }

    grid.sync();

    // ---------------- P4: pass B (items 0..767) ----------------------------
    for (int w = bid; w < 768; w += GRID) {
        const int i    = w >> 8;
        const int rem  = w & 255;
        const int b0   = (rem >> 4) << 2;
        const int dc   = rem & 15;
        const int ln   = t & 31;
        const int d    = (dc << 5) + ln;
        const int esec = t >> 5;
        const int jB   = (i == 2) ? 1 : 2;

        const float cl = cons[i] * LOG2E;
        float a[4];
        const float* uBp[4];
#pragma unroll
        for (int bb = 0; bb < 4; ++bb) {
            a[bb]   = wf[(size_t)i * BD + (b0 + bb) * D_ + d] * (INVSCALE * LOG2E);
            uBp[bb] = wf + (size_t)jB * BD + (b0 + bb) * D_ + (esec << 6);
        }
        const float* hp = HT + ((size_t)(i << 9) + (esec << 6)) * D_ + d;

        float sB[4] = {0.f, 0.f, 0.f, 0.f};
        float dB[4] = {0.f, 0.f, 0.f, 0.f};
#pragma unroll 2
        for (int e = 0; e < 64; e += 4) {
            float hh[4];
#pragma unroll
            for (int k = 0; k < 4; ++k) hh[k] = hp[(size_t)(e + k) * D_];
#pragma unroll
            for (int bb = 0; bb < 4; ++bb) {
                const float4 u4 = *(const float4*)(uBp[bb] + e);
                const float uu[4] = {u4.x, u4.y, u4.z, u4.w};
#pragma unroll
                for (int k = 0; k < 4; ++k) {
                    const float tt = a[bb] * uu[k];
                    const float df = tt - hh[k];
                    const float mm = fminf(fmaxf(df, -cl), cl);
                    const float f  = fmaf(0.8f, hh[k] + mm, 0.2f * tt);
                    const float p  = __builtin_amdgcn_exp2f(f);
                    sB[bb] += p;
                    dB[bb] = fmaf(p, uu[k], dB[bb]);
                }
            }
        }

        float2* part = (float2*)smem;            // [4][256]
#pragma unroll
        for (int bb = 0; bb < 4; ++bb)
            part[bb * 256 + t] = make_float2(sB[bb], dB[bb]);
        __syncthreads();
        if (t < 128) {
            const int bb = t >> 5;
            const int l  = t & 31;
            float Ss = 0.f, Sd = 0.f;
#pragma unroll
            for (int k = 0; k < 8; ++k) {
                const float2 pp = part[bb * 256 + l + (k << 5)];
                Ss += pp.x; Sd += pp.y;
            }
            const float gB = sigmoidf(gamma[i * 3 + jB]);
            const float pv = gB * (Sd / Ss + mbias[i * 3 + jB] * Ssum[jB * B_ + b0 + bb]);
            atomicAdd(&out[(b0 + bb) * D_ + (dc << 5) + l], pv * (1.f / 6.f));
        }
        __syncthreads();                          // protect part reuse
    }
}

// ===========================================================================
// Fallback: R7 4-kernel path (used only if cooperative launch is rejected).
// ===========================================================================
__global__ __launch_bounds__(256) void k_proj(
    const float* __restrict__ x, const float* __restrict__ pW,
    const float* __restrict__ gamma, float* __restrict__ ypart,
    float* __restrict__ out)
{
    const int m    = blockIdx.x >> 8;
    const int r    = blockIdx.x & 255;
    const int kq   = r >> 6;
    const int rem2 = r & 63;
    const int dh   = rem2 >> 5;
    const int bp   = rem2 & 31;
    const int b0   = bp << 1;
    const int t    = threadIdx.x;
    const int d    = (dh << 8) + t;

    if (blockIdx.x < 128)
        out[(blockIdx.x << 8) + t] = 0.f;

    __shared__ __align__(16) float4 xs[2][32];
    if (t < 64) {
        const int rr = t >> 5, cc = t & 31;
        xs[rr][cc] = ((const float4*)(x + (size_t)(m * B_ + b0 + rr) * D_ + kq * 128))[cc];
    }
    __syncthreads();

    const float4* wr = (const float4*)(pW + (size_t)m * D_ * D_ + (size_t)d * D_ + kq * 128);
    float acc0 = 0.f, acc1 = 0.f;
#pragma unroll
    for (int k = 0; k < 32; ++k) {
        const float4 w = wr[k];
        const float4 a = xs[0][k];
        const float4 b = xs[1][k];
        acc0 = fmaf(w.x, a.x, acc0); acc0 = fmaf(w.y, a.y, acc0);
        acc0 = fmaf(w.z, a.z, acc0); acc0 = fmaf(w.w, a.w, acc0);
        acc1 = fmaf(w.x, b.x, acc1); acc1 = fmaf(w.y, b.y, acc1);
        acc1 = fmaf(w.z, b.z, acc1); acc1 = fmaf(w.w, b.w, acc1);
    }
    const size_t idx0 = (size_t)(m * B_ + b0) * 2048 + kq * 512 + d;
    ypart[idx0]        = acc0;
    ypart[idx0 + 2048] = acc1;

    if (blockIdx.x == 0 && t == 0) {
        const float g01 = sigmoidf(gamma[1]), g02 = sigmoidf(gamma[2]);
        const float g10 = sigmoidf(gamma[3]), g12 = sigmoidf(gamma[5]);
        const float g20 = sigmoidf(gamma[6]), g21 = sigmoidf(gamma[7]);
        const float s0 = 0.5f * (g01 + g02);
        const float s1 = 0.5f * (g10 + g12);
        const float s2 = 0.5f * (g20 + g21);
        const float mx = fmaxf(s0, fmaxf(s1, s2));
        const float e0 = __expf(s0 - mx), e1 = __expf(s1 - mx), e2 = __expf(s2 - mx);
        const float den = e0 + e1 + e2;
        out[BD + 0] = e0 / den;
        out[BD + 1] = e1 / den;
        out[BD + 2] = e2 / den;
    }
}

__global__ __launch_bounds__(512) void k_lnmlp(
    const float* __restrict__ ypart, const float* __restrict__ pb,
    const float* __restrict__ lg, const float* __restrict__ lb,
    const float* __restrict__ W1, const float* __restrict__ b1,
    const float* __restrict__ W2, const float* __restrict__ b2,
    float* __restrict__ wf, float* __restrict__ Ssum,
    float* __restrict__ out)
{
    const int m = blockIdx.x >> 6;
    const int b = blockIdx.x & 63;
    const int t = threadIdx.x;
    __shared__ __align__(16) float ps[D_];
    __shared__ __align__(16) float hs[H4];
    __shared__ __align__(16) float hpart[512];
    __shared__ float red[8];

    const size_t rbase = (size_t)(m * B_ + b) * 2048;
    const float y = ypart[rbase + t] + ypart[rbase + 512 + t]
                  + ypart[rbase + 1024 + t] + ypart[rbase + 1536 + t]
                  + pb[m * D_ + t];

    float s = wave_sum64(y);
    if ((t & 63) == 0) red[t >> 6] = s;
    __syncthreads();
    const float mean = (red[0]+red[1]+red[2]+red[3]+red[4]+red[5]+red[6]+red[7]) * (1.f / D_);
    __syncthreads();
    const float v = y - mean;
    float vs = wave_sum64(v * v);
    if ((t & 63) == 0) red[t >> 6] = vs;
    __syncthreads();
    const float inv = rsqrtf((red[0]+red[1]+red[2]+red[3]+red[4]+red[5]+red[6]+red[7]) * (1.f / D_) + 1e-5f);
    const float p = fmaxf(fmaf(v * inv, lg[m * D_ + t], lb[m * D_ + t]), 0.f);
    ps[t] = p;
    __syncthreads();

    {
        const int r = t & 127, seg = t >> 7;
        const float4* w1 = (const float4*)(W1 + ((size_t)m * H4 + r) * D_) + (seg << 5);
        const float4* pv = (const float4*)ps + (seg << 5);
        float a1 = 0.f;
#pragma unroll
        for (int k = 0; k < 32; ++k) {
            const float4 w = w1[k], pp = pv[k];
            a1 = fmaf(w.x, pp.x, a1); a1 = fmaf(w.y, pp.y, a1);
            a1 = fmaf(w.z, pp.z, a1); a1 = fmaf(w.w, pp.w, a1);
        }
        hpart[t] = a1;
    }
    __syncthreads();
    if (t < H4)
        hs[t] = fmaxf(hpart[t] + hpart[t + 128] + hpart[t + 256] + hpart[t + 384]
                      + b1[m * H4 + t], 0.f);
    __syncthreads();

    const float4* w2 = (const float4*)(W2 + ((size_t)m * D_ + t) * H4);
    const float4* hv = (const float4*)hs;
    float a2 = 0.f;
#pragma unroll
    for (int k = 0; k < H4 / 4; ++k) {
        const float4 w = w2[k], hh = hv[k];
        a2 = fmaf(w.x, hh.x, a2); a2 = fmaf(w.y, hh.y, a2);
        a2 = fmaf(w.z, hh.z, a2); a2 = fmaf(w.w, hh.w, a2);
    }
    const float cw = sigmoidf(a2 + b2[m * D_ + t]);
    const float wv = p * cw;
    wf[(size_t)(m * B_ + b) * D_ + t] = wv;
    atomicAdd(&out[b * D_ + t], wv * (1.f / 3.f));

    float tot = wave_sum64(wv);
    if ((t & 63) == 0) red[t >> 6] = tot;
    __syncthreads();
    if (t == 0)
        Ssum[m * B_ + b] = red[0]+red[1]+red[2]+red[3]+red[4]+red[5]+red[6]+red[7];
}

__global__ __launch_bounds__(256) void k_fuseAH(
    const float* __restrict__ wf, const float* __restrict__ constraint,
    const float* __restrict__ gamma, const float* __restrict__ mbias,
    const float* __restrict__ Ssum, float* __restrict__ HT,
    float* __restrict__ out)
{
    const int t = threadIdx.x;

    if (blockIdx.x < 768) {
        const int i    = blockIdx.x >> 8;
        const int rem  = blockIdx.x & 255;
        const int b0   = (rem >> 4) << 2;
        const int dc   = rem & 15;
        const int ln   = t & 31;
        const int d    = (dc << 5) + ln;
        const int esec = t >> 5;
        const int jA   = (i == 0) ? 1 : 0;

        const float c08 = constraint[i] * (0.8f * LOG2E);
        float a08[4], a02[4];
        const float* uAp[4];
#pragma unroll
        for (int bb = 0; bb < 4; ++bb) {
            const float a = wf[(size_t)i * BD + (b0 + bb) * D_ + d];
            a08[bb] = a * (0.8f * INVSCALE * LOG2E);
            a02[bb] = a * (0.2f * INVSCALE * LOG2E);
            uAp[bb] = wf + (size_t)jA * BD + (b0 + bb) * D_ + (esec << 6);
        }

        float sA[4] = {0.f, 0.f, 0.f, 0.f};
        float dA[4] = {0.f, 0.f, 0.f, 0.f};
#pragma unroll 2
        for (int e = 0; e < 64; e += 4) {
#pragma unroll
            for (int bb = 0; bb < 4; ++bb) {
                const float4 u4 = *(const float4*)(uAp[bb] + e);
                const float uu[4] = {u4.x, u4.y, u4.z, u4.w};
#pragma unroll
                for (int k = 0; k < 4; ++k) {
                    const float v1 = a08[bb] * uu[k];
                    const float v2 = fminf(v1, c08);
                    const float f  = fmaf(a02[bb], uu[k], v2);
                    const float p  = __builtin_amdgcn_exp2f(f);
                    sA[bb] += p;
                    dA[bb] = fmaf(p, uu[k], dA[bb]);
                }
            }
        }

        __shared__ __align__(8) float2 part[4][256];
#pragma unroll
        for (int bb = 0; bb < 4; ++bb)
            part[bb][t] = make_float2(sA[bb], dA[bb]);
        __syncthreads();
        if (t < 128) {
            const int bb = t >> 5;
            const int l  = t & 31;
            float Ss = 0.f, Sd = 0.f;
#pragma unroll
            for (int k = 0; k < 8; ++k) {
                const float2 pp = part[bb][l + (k << 5)];
                Ss += pp.x; Sd += pp.y;
            }
            const float gA = sigmoidf(gamma[i * 3 + jA]);
            const float pv = gA * (Sd / Ss + mbias[i * 3 + jA] * Ssum[jA * B_ + b0 + bb]);
            atomicAdd(&out[(b0 + bb) * D_ + (dc << 5) + l], pv * (1.f / 6.f));
        }
        return;
    }

    const int hb = blockIdx.x - 768;
    const int i  = hb >> 7;
    const int e0 = (hb & 127) << 2;
    const int j  = (i == 0) ? 1 : 0;
    const float c = constraint[i];
    const float* wfi = wf + (size_t)i * BD;
    const float* wfj = wf + (size_t)j * BD;

    float h0[4] = {0.f, 0.f, 0.f, 0.f};
    float h1[4] = {0.f, 0.f, 0.f, 0.f};
#pragma unroll 2
    for (int b = 0; b < B_; ++b) {
        const float a0 = wfi[b * D_ + t]       * INVSCALE;
        const float a1 = wfi[b * D_ + t + 256] * INVSCALE;
        const float4 u4 = *(const float4*)(wfj + b * D_ + e0);
        const float uu[4] = {u4.x, u4.y, u4.z, u4.w};
#pragma unroll
        for (int k = 0; k < 4; ++k) {
            float tt = a0 * uu[k]; float mm = fminf(tt, c);
            h0[k] = fmaf(0.8f, mm, fmaf(0.2f, tt, h0[k]));
            tt = a1 * uu[k]; mm = fminf(tt, c);
            h1[k] = fmaf(0.8f, mm, fmaf(0.2f, tt, h1[k]));
        }
    }
    const float hsc = LOG2E / (float)(B_ * HIST_);
    float* r0 = HT + ((size_t)(i << 9) + e0) * D_;
#pragma unroll
    for (int k = 0; k < 4; ++k) {
        r0[(size_t)k * D_ + t]       = h0[k] * hsc;
        r0[(size_t)k * D_ + t + 256] = h1[k] * hsc;
    }
}

__global__ __launch_bounds__(256) void k_passB(
    const float* __restrict__ wf, const float* __restrict__ constraint,
    const float* __restrict__ gamma, const float* __restrict__ mbias,
    const float* __restrict__ HT, const float* __restrict__ Ssum,
    float* __restrict__ out)
{
    const int i    = blockIdx.x >> 8;
    const int rem  = blockIdx.x & 255;
    const int b0   = (rem >> 4) << 2;
    const int dc   = rem & 15;
    const int t    = threadIdx.x;
    const int ln   = t & 31;
    const int d    = (dc << 5) + ln;
    const int esec = t >> 5;
    const int jB   = (i == 2) ? 1 : 2;

    const float cl = constraint[i] * LOG2E;
    float a[4];
    const float* uBp[4];
#pragma unroll
    for (int bb = 0; bb < 4; ++bb) {
        a[bb]  = wf[(size_t)i * BD + (b0 + bb) * D_ + d] * (INVSCALE * LOG2E);
        uBp[bb] = wf + (size_t)jB * BD + (b0 + bb) * D_ + (esec << 6);
    }
    const float* hp = HT + ((size_t)(i << 9) + (esec << 6)) * D_ + d;

    float sB[4] = {0.f, 0.f, 0.f, 0.f};
    float dB[4] = {0.f, 0.f, 0.f, 0.f};
#pragma unroll 2
    for (int e = 0; e < 64; e += 4) {
        float hh[4];
#pragma unroll
        for (int k = 0; k < 4; ++k) hh[k] = hp[(size_t)(e + k) * D_];
#pragma unroll
        for (int bb = 0; bb < 4; ++bb) {
            const float4 u4 = *(const float4*)(uBp[bb] + e);
            const float uu[4] = {u4.x, u4.y, u4.z, u4.w};
#pragma unroll
            for (int k = 0; k < 4; ++k) {
                const float tt = a[bb] * uu[k];
                const float df = tt - hh[k];
                const float mm = fminf(fmaxf(df, -cl), cl);
                const float f  = fmaf(0.8f, hh[k] + mm, 0.2f * tt);
                const float p  = __builtin_amdgcn_exp2f(f);
                sB[bb] += p;
                dB[bb] = fmaf(p, uu[k], dB[bb]);
            }
        }
    }

    __shared__ __align__(8) float2 part[4][256];
#pragma unroll
    for (int bb = 0; bb < 4; ++bb)
        part[bb][t] = make_float2(sB[bb], dB[bb]);
    __syncthreads();
    if (t < 128) {
        const int bb = t >> 5;
        const int l  = t & 31;
        float Ss = 0.f, Sd = 0.f;
#pragma unroll
        for (int k = 0; k < 8; ++k) {
            const float2 pp = part[bb][l + (k << 5)];
            Ss += pp.x; Sd += pp.y;
        }
        const float gB = sigmoidf(gamma[i * 3 + jB]);
        const float pv = gB * (Sd / Ss + mbias[i * 3 + jB] * Ssum[jB * B_ + b0 + bb]);
        atomicAdd(&out[(b0 + bb) * D_ + (dc << 5) + l], pv * (1.f / 6.f));
    }
}

// ---------------------------------------------------------------------------
extern "C" void kernel_launch(void* const* d_in, const int* in_sizes, int n_in,
                              void* d_out, int out_size, void* d_ws, size_t ws_size,
                              hipStream_t stream) {
    const float* x    = (const float*)d_in[0];
    const float* pW   = (const float*)d_in[1];
    const float* pb   = (const float*)d_in[2];
    const float* lg   = (const float*)d_in[3];
    const float* lb   = (const float*)d_in[4];
    const float* W1   = (const float*)d_in[5];
    const float* b1   = (const float*)d_in[6];
    const float* W2   = (const float*)d_in[7];
    const float* b2   = (const float*)d_in[8];
    const float* gamma= (const float*)d_in[9];
    const float* mb   = (const float*)d_in[10];
    const float* cons = (const float*)d_in[11];
    float* out = (float*)d_out;

    float* ws    = (float*)d_ws;
    float* wf    = ws;                 // 98304 floats
    float* Ssum  = ws + 98304;         // 192
    float* HT    = ws + 98496;         // 786432 (HT[i][e][d], *LOG2E)
    float* ypart = ws + 884928;        // 393216

    void* args[] = { (void*)&x, (void*)&pW, (void*)&pb, (void*)&lg, (void*)&lb,
                     (void*)&W1, (void*)&b1, (void*)&W2, (void*)&b2, (void*)&gamma,
                     (void*)&mb, (void*)&cons, (void*)&wf, (void*)&Ssum,
                     (void*)&HT, (void*)&ypart, (void*)&out };
    hipError_t err = hipLaunchCooperativeKernel(
        reinterpret_cast<const void*>(k_fused), dim3(GRID), dim3(256),
        (void**)args, 0, stream);
    if (err != hipSuccess) {
        // Fallback: sequential 4-kernel path
        k_proj  <<<dim3(768),     dim3(256), 0, stream>>>(x, pW, gamma, ypart, out);
        k_lnmlp <<<dim3(M_ * B_), dim3(512), 0, stream>>>(ypart, pb, lg, lb, W1, b1, W2, b2, wf, Ssum, out);
        k_fuseAH<<<dim3(1152),    dim3(256), 0, stream>>>(wf, cons, gamma, mb, Ssum, HT, out);
        k_passB <<<dim3(768),     dim3(256), 0, stream>>>(wf, cons, gamma, mb, HT, Ssum, out);
    }
}

// Round 5
// 180.265 us; speedup vs baseline: 2.0427x; 2.0427x over previous
//
#include <hip/hip_runtime.h>
#include <math.h>

#define M_ 3
#define B_ 64
#define D_ 512
#define H4 128     // D/4
#define HIST_ 5
#define BD (B_ * D_)        // 32768
#define INVSCALE 0.04419417382415922f   // 1/sqrt(512)
#define LOG2E 1.4426950408889634f

__device__ __forceinline__ float wave_sum64(float v) {
#pragma unroll
    for (int o = 32; o >= 1; o >>= 1) v += __shfl_xor(v, o, 64);
    return v;
}

__device__ __forceinline__ float sigmoidf(float x) {
    return 1.0f / (1.0f + __expf(-x));
}

// ---------------------------------------------------------------------------
// k_projln: fused proj GEMM + LayerNorm + ReLU + MLP + wf + Ssum.
// grid = 192 blocks (m,b), 512 threads (thread = d).
// Proj dot is computed in 4 k-quarters summed in the same order as the old
// ypart[kq] path -> bit-identical y. Writes wf, Ssum; block 0 writes the
// attention weights. Does NOT touch out[0..BD) (k_pass stores it once).
// ---------------------------------------------------------------------------
__global__ __launch_bounds__(512) void k_projln(
    const float* __restrict__ x, const float* __restrict__ pW,
    const float* __restrict__ pb, const float* __restrict__ lg,
    const float* __restrict__ lb, const float* __restrict__ W1,
    const float* __restrict__ b1, const float* __restrict__ W2,
    const float* __restrict__ b2, const float* __restrict__ gamma,
    float* __restrict__ wf, float* __restrict__ Ssum,
    float* __restrict__ out)
{
    const int m = blockIdx.x >> 6;
    const int b = blockIdx.x & 63;
    const int t = threadIdx.x;
    __shared__ __align__(16) float xs[D_];
    __shared__ __align__(16) float ps[D_];
    __shared__ __align__(16) float hpart[512];
    __shared__ __align__(16) float hs[H4];
    __shared__ float red[8];

    xs[t] = x[(size_t)(m * B_ + b) * D_ + t];
    __syncthreads();

    // proj dot: thread t owns output dim d = t. 4 k-quarters, summed in the
    // same order as the old ypart quarters (bit-identical).
    const float4* wr = (const float4*)(pW + ((size_t)m * D_ + t) * D_);
    const float4* xv = (const float4*)xs;
    float q[4];
#pragma unroll
    for (int qq = 0; qq < 4; ++qq) {
        float acc = 0.f;
#pragma unroll
        for (int k = 0; k < 32; ++k) {
            const float4 w = wr[(qq << 5) + k];
            const float4 a = xv[(qq << 5) + k];
            acc = fmaf(w.x, a.x, acc); acc = fmaf(w.y, a.y, acc);
            acc = fmaf(w.z, a.z, acc); acc = fmaf(w.w, a.w, acc);
        }
        q[qq] = acc;
    }
    const float y = q[0] + q[1] + q[2] + q[3] + pb[m * D_ + t];

    float s = wave_sum64(y);
    if ((t & 63) == 0) red[t >> 6] = s;
    __syncthreads();
    const float mean = (red[0]+red[1]+red[2]+red[3]+red[4]+red[5]+red[6]+red[7]) * (1.f / D_);
    __syncthreads();
    const float v = y - mean;
    float vs = wave_sum64(v * v);
    if ((t & 63) == 0) red[t >> 6] = vs;
    __syncthreads();
    const float inv = rsqrtf((red[0]+red[1]+red[2]+red[3]+red[4]+red[5]+red[6]+red[7]) * (1.f / D_) + 1e-5f);
    const float p = fmaxf(fmaf(v * inv, lg[m * D_ + t], lb[m * D_ + t]), 0.f);
    ps[t] = p;
    __syncthreads();

    // MLP1: r = t&127, seg = t>>7 (4-way K-split)
    {
        const int r = t & 127, seg = t >> 7;
        const float4* w1 = (const float4*)(W1 + ((size_t)m * H4 + r) * D_) + (seg << 5);
        const float4* pv = (const float4*)ps + (seg << 5);
        float a1 = 0.f;
#pragma unroll
        for (int k = 0; k < 32; ++k) {
            const float4 w = w1[k], pp = pv[k];
            a1 = fmaf(w.x, pp.x, a1); a1 = fmaf(w.y, pp.y, a1);
            a1 = fmaf(w.z, pp.z, a1); a1 = fmaf(w.w, pp.w, a1);
        }
        hpart[t] = a1;
    }
    __syncthreads();
    if (t < H4)
        hs[t] = fmaxf(hpart[t] + hpart[t + 128] + hpart[t + 256] + hpart[t + 384]
                      + b1[m * H4 + t], 0.f);
    __syncthreads();

    // MLP2
    const float4* w2 = (const float4*)(W2 + ((size_t)m * D_ + t) * H4);
    const float4* hv = (const float4*)hs;
    float a2 = 0.f;
#pragma unroll
    for (int k = 0; k < H4 / 4; ++k) {
        const float4 w = w2[k], hh = hv[k];
        a2 = fmaf(w.x, hh.x, a2); a2 = fmaf(w.y, hh.y, a2);
        a2 = fmaf(w.z, hh.z, a2); a2 = fmaf(w.w, hh.w, a2);
    }
    const float cw = sigmoidf(a2 + b2[m * D_ + t]);
    const float wv = p * cw;
    wf[(size_t)(m * B_ + b) * D_ + t] = wv;

    float tot = wave_sum64(wv);
    if ((t & 63) == 0) red[t >> 6] = tot;
    __syncthreads();
    if (t == 0)
        Ssum[m * B_ + b] = red[0]+red[1]+red[2]+red[3]+red[4]+red[5]+red[6]+red[7];

    if (blockIdx.x == 0 && t == 0) {
        const float g01 = sigmoidf(gamma[1]), g02 = sigmoidf(gamma[2]);
        const float g10 = sigmoidf(gamma[3]), g12 = sigmoidf(gamma[5]);
        const float g20 = sigmoidf(gamma[6]), g21 = sigmoidf(gamma[7]);
        const float s0 = 0.5f * (g01 + g02);
        const float s1 = 0.5f * (g10 + g12);
        const float s2 = 0.5f * (g20 + g21);
        const float mx = fmaxf(s0, fmaxf(s1, s2));
        const float e0 = __expf(s0 - mx), e1 = __expf(s1 - mx), e2 = __expf(s2 - mx);
        const float den = e0 + e1 + e2;
        out[BD + 0] = e0 / den;
        out[BD + 1] = e1 / den;
        out[BD + 2] = e2 / den;
    }
}

// ---------------------------------------------------------------------------
// k_hist: history matrices, TRANSPOSED HT[i][e][d] pre-scaled by LOG2E.
// grid = 384 blocks: block=(i, e-quad), thread = d & d+256.
// ---------------------------------------------------------------------------
__global__ __launch_bounds__(256) void k_hist(
    const float* __restrict__ wf, const float* __restrict__ cons,
    float* __restrict__ HT)
{
    const int t  = threadIdx.x;
    const int i  = blockIdx.x >> 7;         // 128 blocks per mode
    const int e0 = (blockIdx.x & 127) << 2;
    const int j  = (i == 0) ? 1 : 0;
    const float c = cons[i];
    const float* wfi = wf + (size_t)i * BD;
    const float* wfj = wf + (size_t)j * BD;

    float h0[4] = {0.f, 0.f, 0.f, 0.f};
    float h1[4] = {0.f, 0.f, 0.f, 0.f};
#pragma unroll 2
    for (int b = 0; b < B_; ++b) {
        const float a0 = wfi[b * D_ + t]       * INVSCALE;
        const float a1 = wfi[b * D_ + t + 256] * INVSCALE;
        const float4 u4 = *(const float4*)(wfj + b * D_ + e0);
        const float uu[4] = {u4.x, u4.y, u4.z, u4.w};
#pragma unroll
        for (int k = 0; k < 4; ++k) {
            float tt = a0 * uu[k]; float mm = fminf(tt, c);
            h0[k] = fmaf(0.8f, mm, fmaf(0.2f, tt, h0[k]));
            tt = a1 * uu[k]; mm = fminf(tt, c);
            h1[k] = fmaf(0.8f, mm, fmaf(0.2f, tt, h1[k]));
        }
    }
    const float hsc = LOG2E / (float)(B_ * HIST_);
    float* r0 = HT + ((size_t)(i << 9) + e0) * D_;
#pragma unroll
    for (int k = 0; k < 4; ++k) {
        r0[(size_t)k * D_ + t]       = h0[k] * hsc;
        r0[(size_t)k * D_ + t + 256] = h1[k] * hsc;
    }
}

// ---------------------------------------------------------------------------
// k_pass: ALL 6 (i,j) softmax-dot passes per block; single non-atomic store.
// grid = 512 blocks: block=(b-pair, 32-d chunk), 256 thr = 32 d x 8 e-secs.
// passA uses hist=0 (pre-scaled a08/a02 min() form); passB uses HT.
// Tail (t<64): reduce 8 e-sections, accumulate pv over the i-loop, then
// out[b,d] = sum(pv)/6 + (wf0+wf1+wf2)/3  -- no atomics, no pre-zero.
// ---------------------------------------------------------------------------
__global__ __launch_bounds__(256) void k_pass(
    const float* __restrict__ wf, const float* __restrict__ cons,
    const float* __restrict__ gamma, const float* __restrict__ mbias,
    const float* __restrict__ HT, const float* __restrict__ Ssum,
    float* __restrict__ out)
{
    const int bg   = blockIdx.x >> 4;       // 0..31 (b-pair)
    const int dc   = blockIdx.x & 15;
    const int b0   = bg << 1;
    const int t    = threadIdx.x;
    const int ln   = t & 31;
    const int d    = (dc << 5) + ln;
    const int esec = t >> 5;                // 0..7, 64 e's each

    __shared__ __align__(16) float4 part[2][256];
    float oacc = 0.f;                        // used by t<64

#pragma unroll
    for (int i = 0; i < 3; ++i) {
        const int jA = (i == 0) ? 1 : 0;
        const int jB = (i == 2) ? 1 : 2;
        const float c08 = cons[i] * (0.8f * LOG2E);
        const float cl  = cons[i] * LOG2E;

        float a08[2], a02[2], aB[2];
        const float* uA[2];
        const float* uB[2];
#pragma unroll
        for (int bb = 0; bb < 2; ++bb) {
            const float a = wf[(size_t)i * BD + (b0 + bb) * D_ + d];
            a08[bb] = a * (0.8f * INVSCALE * LOG2E);
            a02[bb] = a * (0.2f * INVSCALE * LOG2E);
            aB[bb]  = a * (INVSCALE * LOG2E);
            uA[bb] = wf + (size_t)jA * BD + (b0 + bb) * D_ + (esec << 6);
            uB[bb] = wf + (size_t)jB * BD + (b0 + bb) * D_ + (esec << 6);
        }
        const float* hp = HT + ((size_t)(i << 9) + (esec << 6)) * D_ + d;

        float sA[2] = {0.f, 0.f}, dA[2] = {0.f, 0.f};
        float sB[2] = {0.f, 0.f}, dB[2] = {0.f, 0.f};
#pragma unroll 2
        for (int e = 0; e < 64; e += 4) {
            float hh[4];
#pragma unroll
            for (int k = 0; k < 4; ++k) hh[k] = hp[(size_t)(e + k) * D_];
#pragma unroll
            for (int bb = 0; bb < 2; ++bb) {
                const float4 uA4 = *(const float4*)(uA[bb] + e);
                const float4 uB4 = *(const float4*)(uB[bb] + e);
                const float ua[4] = {uA4.x, uA4.y, uA4.z, uA4.w};
                const float ub[4] = {uB4.x, uB4.y, uB4.z, uB4.w};
#pragma unroll
                for (int k = 0; k < 4; ++k) {
                    // pass A (hist = 0): f = min(a08*u, c08) + a02*u
                    const float v1 = a08[bb] * ua[k];
                    const float v2 = fminf(v1, c08);
                    const float fA = fmaf(a02[bb], ua[k], v2);
                    const float pA = __builtin_amdgcn_exp2f(fA);
                    sA[bb] += pA;
                    dA[bb] = fmaf(pA, ua[k], dA[bb]);
                    // pass B: f = 0.8*(h + clip(a*u - h)) + 0.2*a*u
                    const float tt = aB[bb] * ub[k];
                    const float df = tt - hh[k];
                    const float mm = fminf(fmaxf(df, -cl), cl);
                    const float fB = fmaf(0.8f, hh[k] + mm, 0.2f * tt);
                    const float pB = __builtin_amdgcn_exp2f(fB);
                    sB[bb] += pB;
                    dB[bb] = fmaf(pB, ub[k], dB[bb]);
                }
            }
        }

        part[0][t] = make_float4(sA[0], dA[0], sB[0], dB[0]);
        part[1][t] = make_float4(sA[1], dA[1], sB[1], dB[1]);
        __syncthreads();
        if (t < 64) {
            const int bb = t >> 5;
            const int l  = t & 31;
            float SsA = 0.f, SdA = 0.f, SsB = 0.f, SdB = 0.f;
#pragma unroll
            for (int k = 0; k < 8; ++k) {
                const float4 pp = part[bb][l + (k << 5)];
                SsA += pp.x; SdA += pp.y; SsB += pp.z; SdB += pp.w;
            }
            const float gA = sigmoidf(gamma[i * 3 + jA]);
            const float gB = sigmoidf(gamma[i * 3 + jB]);
            oacc += gA * (SdA / SsA + mbias[i * 3 + jA] * Ssum[jA * B_ + b0 + bb]);
            oacc += gB * (SdB / SsB + mbias[i * 3 + jB] * Ssum[jB * B_ + b0 + bb]);
        }
        __syncthreads();                      // protect part reuse next i
    }

    if (t < 64) {
        const int bb = t >> 5;
        const int l  = t & 31;
        const int od = (dc << 5) + l;
        const float w0 = wf[(size_t)0 * BD + (b0 + bb) * D_ + od];
        const float w1 = wf[(size_t)1 * BD + (b0 + bb) * D_ + od];
        const float w2 = wf[(size_t)2 * BD + (b0 + bb) * D_ + od];
        out[(b0 + bb) * D_ + od] = oacc * (1.f / 6.f) + (w0 + w1 + w2) * (1.f / 3.f);
    }
}

// ---------------------------------------------------------------------------
extern "C" void kernel_launch(void* const* d_in, const int* in_sizes, int n_in,
                              void* d_out, int out_size, void* d_ws, size_t ws_size,
                              hipStream_t stream) {
    const float* x    = (const float*)d_in[0];
    const float* pW   = (const float*)d_in[1];
    const float* pb   = (const float*)d_in[2];
    const float* lg   = (const float*)d_in[3];
    const float* lb   = (const float*)d_in[4];
    const float* W1   = (const float*)d_in[5];
    const float* b1   = (const float*)d_in[6];
    const float* W2   = (const float*)d_in[7];
    const float* b2   = (const float*)d_in[8];
    const float* gamma= (const float*)d_in[9];
    const float* mb   = (const float*)d_in[10];
    const float* cons = (const float*)d_in[11];
    float* out = (float*)d_out;

    float* ws   = (float*)d_ws;
    float* wf   = ws;                 // 98304 floats
    float* Ssum = ws + 98304;         // 192
    float* HT   = ws + 98496;         // 786432 (HT[i][e][d], *LOG2E)

    k_projln<<<dim3(M_ * B_), dim3(512), 0, stream>>>(x, pW, pb, lg, lb, W1, b1, W2, b2, gamma, wf, Ssum, out);
    k_hist  <<<dim3(384),     dim3(256), 0, stream>>>(wf, cons, HT);
    k_pass  <<<dim3(512),     dim3(256), 0, stream>>>(wf, cons, gamma, mb, HT, Ssum, out);
}

// Round 6
// 177.350 us; speedup vs baseline: 2.0762x; 1.0164x over previous
//
#include <hip/hip_runtime.h>
#include <math.h>

#define M_ 3
#define B_ 64
#define D_ 512
#define H4 128     // D/4
#define HIST_ 5
#define BD (B_ * D_)        // 32768
#define INVSCALE 0.04419417382415922f   // 1/sqrt(512)
#define LOG2E 1.4426950408889634f

__device__ __forceinline__ float wave_sum64(float v) {
#pragma unroll
    for (int o = 32; o >= 1; o >>= 1) v += __shfl_xor(v, o, 64);
    return v;
}

__device__ __forceinline__ float sigmoidf(float x) {
    return 1.0f / (1.0f + __expf(-x));
}

// ---------------------------------------------------------------------------
// k_projln v2: fused proj GEMM + LN + ReLU + MLP + wf + Ssum.
// grid = 192 blocks (m,b), 1024 threads. R5's 512-thr version was
// latency-bound (VALUBusy 3%, occupancy 16%, VGPR 36 -> ~4 loads in flight,
// 128-long load chains). v2: 2x waves (1024 thr: thread=(K-half, d)) and
// forced 8-deep load batches -> chains of 64 loads with 8 in flight.
// ---------------------------------------------------------------------------
__global__ __launch_bounds__(1024) void k_projln(
    const float* __restrict__ x, const float* __restrict__ pW,
    const float* __restrict__ pb, const float* __restrict__ lg,
    const float* __restrict__ lb, const float* __restrict__ W1,
    const float* __restrict__ b1, const float* __restrict__ W2,
    const float* __restrict__ b2, const float* __restrict__ gamma,
    float* __restrict__ wf, float* __restrict__ Ssum,
    float* __restrict__ out)
{
    const int m  = blockIdx.x >> 6;
    const int b  = blockIdx.x & 63;
    const int t  = threadIdx.x;      // 0..1023
    const int d  = t & 511;
    const int kh = t >> 9;           // 0 or 1 (K half)

    __shared__ __align__(16) float xs[D_];
    __shared__ __align__(16) float ps[D_];
    __shared__ __align__(16) float ppart[1024];   // proj partials [kh][d]; reused by MLP2
    __shared__ __align__(16) float hpart[1024];   // MLP1 partials [seg][r]
    __shared__ __align__(16) float hs[H4];
    __shared__ float red[8];

    if (t < D_) xs[t] = x[(size_t)(m * B_ + b) * D_ + t];
    __syncthreads();

    // ---- proj half-dot: thread (kh,d) does 256-length dot = 64 float4,
    //      batched 8-deep for memory-level parallelism.
    {
        const float4* wr = (const float4*)(pW + ((size_t)m * D_ + d) * D_) + (kh << 6);
        const float4* xv = (const float4*)xs + (kh << 6);
        float acc = 0.f;
#pragma unroll
        for (int bch = 0; bch < 8; ++bch) {
            float4 wb[8];
#pragma unroll
            for (int j = 0; j < 8; ++j) wb[j] = wr[(bch << 3) + j];
#pragma unroll
            for (int j = 0; j < 8; ++j) {
                const float4 a = xv[(bch << 3) + j];
                acc = fmaf(wb[j].x, a.x, acc); acc = fmaf(wb[j].y, a.y, acc);
                acc = fmaf(wb[j].z, a.z, acc); acc = fmaf(wb[j].w, a.w, acc);
            }
        }
        ppart[(kh << 9) + d] = acc;
    }
    __syncthreads();

    // ---- LayerNorm (threads < 512; 512 boundary is wave-aligned)
    float y = 0.f;
    if (t < D_) {
        y = ppart[d] + ppart[512 + d] + pb[m * D_ + t];
        float s = wave_sum64(y);
        if ((t & 63) == 0) red[t >> 6] = s;
    }
    __syncthreads();
    const float mean = (red[0]+red[1]+red[2]+red[3]+red[4]+red[5]+red[6]+red[7]) * (1.f / D_);
    __syncthreads();
    float v = 0.f;
    if (t < D_) {
        v = y - mean;
        float vs = wave_sum64(v * v);
        if ((t & 63) == 0) red[t >> 6] = vs;
    }
    __syncthreads();
    const float inv = rsqrtf((red[0]+red[1]+red[2]+red[3]+red[4]+red[5]+red[6]+red[7]) * (1.f / D_) + 1e-5f);
    float p = 0.f;
    if (t < D_) {
        p = fmaxf(fmaf(v * inv, lg[m * D_ + t], lb[m * D_ + t]), 0.f);
        ps[t] = p;
    }
    __syncthreads();

    // ---- MLP1: 8-way K-split. seg = t>>7 (0..7), r = t&127; 64-length dot
    //      = 16 float4, batched 8-deep.
    {
        const int r = t & 127, seg = t >> 7;
        const float4* w1 = (const float4*)(W1 + ((size_t)m * H4 + r) * D_) + (seg << 4);
        const float4* pv = (const float4*)ps + (seg << 4);
        float a1 = 0.f;
#pragma unroll
        for (int bch = 0; bch < 2; ++bch) {
            float4 wb[8];
#pragma unroll
            for (int j = 0; j < 8; ++j) wb[j] = w1[(bch << 3) + j];
#pragma unroll
            for (int j = 0; j < 8; ++j) {
                const float4 a = pv[(bch << 3) + j];
                a1 = fmaf(wb[j].x, a.x, a1); a1 = fmaf(wb[j].y, a.y, a1);
                a1 = fmaf(wb[j].z, a.z, a1); a1 = fmaf(wb[j].w, a.w, a1);
            }
        }
        hpart[(seg << 7) + r] = a1;
    }
    __syncthreads();
    if (t < H4) {
        float h = hpart[t];
#pragma unroll
        for (int s2 = 1; s2 < 8; ++s2) h += hpart[(s2 << 7) + t];
        hs[t] = fmaxf(h + b1[m * H4 + t], 0.f);
    }
    __syncthreads();

    // ---- MLP2: 2-way K-split. thread (kh,d): 64-length half-dot = 16 f4.
    {
        const float4* w2 = (const float4*)(W2 + ((size_t)m * D_ + d) * H4) + (kh << 4);
        const float4* hv = (const float4*)hs + (kh << 4);
        float a2 = 0.f;
#pragma unroll
        for (int bch = 0; bch < 2; ++bch) {
            float4 wb[8];
#pragma unroll
            for (int j = 0; j < 8; ++j) wb[j] = w2[(bch << 3) + j];
#pragma unroll
            for (int j = 0; j < 8; ++j) {
                const float4 a = hv[(bch << 3) + j];
                a2 = fmaf(wb[j].x, a.x, a2); a2 = fmaf(wb[j].y, a.y, a2);
                a2 = fmaf(wb[j].z, a.z, a2); a2 = fmaf(wb[j].w, a.w, a2);
            }
        }
        __syncthreads();                      // ppart reuse (proj partials dead)
        ppart[(kh << 9) + d] = a2;
    }
    __syncthreads();

    if (t < D_) {
        const float cw = sigmoidf(ppart[d] + ppart[512 + d] + b2[m * D_ + t]);
        const float wv = p * cw;
        wf[(size_t)(m * B_ + b) * D_ + t] = wv;
        float tot = wave_sum64(wv);
        if ((t & 63) == 0) red[t >> 6] = tot;
    }
    __syncthreads();
    if (t == 0)
        Ssum[m * B_ + b] = red[0]+red[1]+red[2]+red[3]+red[4]+red[5]+red[6]+red[7];

    if (blockIdx.x == 0 && t == 0) {
        const float g01 = sigmoidf(gamma[1]), g02 = sigmoidf(gamma[2]);
        const float g10 = sigmoidf(gamma[3]), g12 = sigmoidf(gamma[5]);
        const float g20 = sigmoidf(gamma[6]), g21 = sigmoidf(gamma[7]);
        const float s0 = 0.5f * (g01 + g02);
        const float s1 = 0.5f * (g10 + g12);
        const float s2 = 0.5f * (g20 + g21);
        const float mx = fmaxf(s0, fmaxf(s1, s2));
        const float e0 = __expf(s0 - mx), e1 = __expf(s1 - mx), e2 = __expf(s2 - mx);
        const float den = e0 + e1 + e2;
        out[BD + 0] = e0 / den;
        out[BD + 1] = e1 / den;
        out[BD + 2] = e2 / den;
    }
}

// ---------------------------------------------------------------------------
// k_hist: history matrices, TRANSPOSED HT[i][e][d] pre-scaled by LOG2E.
// grid = 384 blocks: block=(i, e-quad), thread = d & d+256.
// ---------------------------------------------------------------------------
__global__ __launch_bounds__(256) void k_hist(
    const float* __restrict__ wf, const float* __restrict__ cons,
    float* __restrict__ HT)
{
    const int t  = threadIdx.x;
    const int i  = blockIdx.x >> 7;         // 128 blocks per mode
    const int e0 = (blockIdx.x & 127) << 2;
    const int j  = (i == 0) ? 1 : 0;
    const float c = cons[i];
    const float* wfi = wf + (size_t)i * BD;
    const float* wfj = wf + (size_t)j * BD;

    float h0[4] = {0.f, 0.f, 0.f, 0.f};
    float h1[4] = {0.f, 0.f, 0.f, 0.f};
#pragma unroll 2
    for (int b = 0; b < B_; ++b) {
        const float a0 = wfi[b * D_ + t]       * INVSCALE;
        const float a1 = wfi[b * D_ + t + 256] * INVSCALE;
        const float4 u4 = *(const float4*)(wfj + b * D_ + e0);
        const float uu[4] = {u4.x, u4.y, u4.z, u4.w};
#pragma unroll
        for (int k = 0; k < 4; ++k) {
            float tt = a0 * uu[k]; float mm = fminf(tt, c);
            h0[k] = fmaf(0.8f, mm, fmaf(0.2f, tt, h0[k]));
            tt = a1 * uu[k]; mm = fminf(tt, c);
            h1[k] = fmaf(0.8f, mm, fmaf(0.2f, tt, h1[k]));
        }
    }
    const float hsc = LOG2E / (float)(B_ * HIST_);
    float* r0 = HT + ((size_t)(i << 9) + e0) * D_;
#pragma unroll
    for (int k = 0; k < 4; ++k) {
        r0[(size_t)k * D_ + t]       = h0[k] * hsc;
        r0[(size_t)k * D_ + t + 256] = h1[k] * hsc;
    }
}

// ---------------------------------------------------------------------------
// k_pass: ALL 6 (i,j) softmax-dot passes per block; single non-atomic store.
// grid = 512 blocks: block=(b-pair, 32-d chunk), 256 thr = 32 d x 8 e-secs.
// passA uses hist=0 (pre-scaled a08/a02 min() form); passB uses HT.
// Tail (t<64): reduce 8 e-sections, accumulate pv over the i-loop, then
// out[b,d] = sum(pv)/6 + (wf0+wf1+wf2)/3  -- no atomics, no pre-zero.
// ---------------------------------------------------------------------------
__global__ __launch_bounds__(256) void k_pass(
    const float* __restrict__ wf, const float* __restrict__ cons,
    const float* __restrict__ gamma, const float* __restrict__ mbias,
    const float* __restrict__ HT, const float* __restrict__ Ssum,
    float* __restrict__ out)
{
    const int bg   = blockIdx.x >> 4;       // 0..31 (b-pair)
    const int dc   = blockIdx.x & 15;
    const int b0   = bg << 1;
    const int t    = threadIdx.x;
    const int ln   = t & 31;
    const int d    = (dc << 5) + ln;
    const int esec = t >> 5;                // 0..7, 64 e's each

    __shared__ __align__(16) float4 part[2][256];
    float oacc = 0.f;                        // used by t<64

#pragma unroll
    for (int i = 0; i < 3; ++i) {
        const int jA = (i == 0) ? 1 : 0;
        const int jB = (i == 2) ? 1 : 2;
        const float c08 = cons[i] * (0.8f * LOG2E);
        const float cl  = cons[i] * LOG2E;

        float a08[2], a02[2], aB[2];
        const float* uA[2];
        const float* uB[2];
#pragma unroll
        for (int bb = 0; bb < 2; ++bb) {
            const float a = wf[(size_t)i * BD + (b0 + bb) * D_ + d];
            a08[bb] = a * (0.8f * INVSCALE * LOG2E);
            a02[bb] = a * (0.2f * INVSCALE * LOG2E);
            aB[bb]  = a * (INVSCALE * LOG2E);
            uA[bb] = wf + (size_t)jA * BD + (b0 + bb) * D_ + (esec << 6);
            uB[bb] = wf + (size_t)jB * BD + (b0 + bb) * D_ + (esec << 6);
        }
        const float* hp = HT + ((size_t)(i << 9) + (esec << 6)) * D_ + d;

        float sA[2] = {0.f, 0.f}, dA[2] = {0.f, 0.f};
        float sB[2] = {0.f, 0.f}, dB[2] = {0.f, 0.f};
#pragma unroll 2
        for (int e = 0; e < 64; e += 4) {
            float hh[4];
#pragma unroll
            for (int k = 0; k < 4; ++k) hh[k] = hp[(size_t)(e + k) * D_];
#pragma unroll
            for (int bb = 0; bb < 2; ++bb) {
                const float4 uA4 = *(const float4*)(uA[bb] + e);
                const float4 uB4 = *(const float4*)(uB[bb] + e);
                const float ua[4] = {uA4.x, uA4.y, uA4.z, uA4.w};
                const float ub[4] = {uB4.x, uB4.y, uB4.z, uB4.w};
#pragma unroll
                for (int k = 0; k < 4; ++k) {
                    // pass A (hist = 0): f = min(a08*u, c08) + a02*u
                    const float v1 = a08[bb] * ua[k];
                    const float v2 = fminf(v1, c08);
                    const float fA = fmaf(a02[bb], ua[k], v2);
                    const float pA = __builtin_amdgcn_exp2f(fA);
                    sA[bb] += pA;
                    dA[bb] = fmaf(pA, ua[k], dA[bb]);
                    // pass B: f = 0.8*(h + clip(a*u - h)) + 0.2*a*u
                    const float tt = aB[bb] * ub[k];
                    const float df = tt - hh[k];
                    const float mm = fminf(fmaxf(df, -cl), cl);
                    const float fB = fmaf(0.8f, hh[k] + mm, 0.2f * tt);
                    const float pB = __builtin_amdgcn_exp2f(fB);
                    sB[bb] += pB;
                    dB[bb] = fmaf(pB, ub[k], dB[bb]);
                }
            }
        }

        part[0][t] = make_float4(sA[0], dA[0], sB[0], dB[0]);
        part[1][t] = make_float4(sA[1], dA[1], sB[1], dB[1]);
        __syncthreads();
        if (t < 64) {
            const int bb = t >> 5;
            const int l  = t & 31;
            float SsA = 0.f, SdA = 0.f, SsB = 0.f, SdB = 0.f;
#pragma unroll
            for (int k = 0; k < 8; ++k) {
                const float4 pp = part[bb][l + (k << 5)];
                SsA += pp.x; SdA += pp.y; SsB += pp.z; SdB += pp.w;
            }
            const float gA = sigmoidf(gamma[i * 3 + jA]);
            const float gB = sigmoidf(gamma[i * 3 + jB]);
            oacc += gA * (SdA / SsA + mbias[i * 3 + jA] * Ssum[jA * B_ + b0 + bb]);
            oacc += gB * (SdB / SsB + mbias[i * 3 + jB] * Ssum[jB * B_ + b0 + bb]);
        }
        __syncthreads();                      // protect part reuse next i
    }

    if (t < 64) {
        const int bb = t >> 5;
        const int l  = t & 31;
        const int od = (dc << 5) + l;
        const float w0 = wf[(size_t)0 * BD + (b0 + bb) * D_ + od];
        const float w1 = wf[(size_t)1 * BD + (b0 + bb) * D_ + od];
        const float w2 = wf[(size_t)2 * BD + (b0 + bb) * D_ + od];
        out[(b0 + bb) * D_ + od] = oacc * (1.f / 6.f) + (w0 + w1 + w2) * (1.f / 3.f);
    }
}

// ---------------------------------------------------------------------------
extern "C" void kernel_launch(void* const* d_in, const int* in_sizes, int n_in,
                              void* d_out, int out_size, void* d_ws, size_t ws_size,
                              hipStream_t stream) {
    const float* x    = (const float*)d_in[0];
    const float* pW   = (const float*)d_in[1];
    const float* pb   = (const float*)d_in[2];
    const float* lg   = (const float*)d_in[3];
    const float* lb   = (const float*)d_in[4];
    const float* W1   = (const float*)d_in[5];
    const float* b1   = (const float*)d_in[6];
    const float* W2   = (const float*)d_in[7];
    const float* b2   = (const float*)d_in[8];
    const float* gamma= (const float*)d_in[9];
    const float* mb   = (const float*)d_in[10];
    const float* cons = (const float*)d_in[11];
    float* out = (float*)d_out;

    float* ws   = (float*)d_ws;
    float* wf   = ws;                 // 98304 floats
    float* Ssum = ws + 98304;         // 192
    float* HT   = ws + 98496;         // 786432 (HT[i][e][d], *LOG2E)

    k_projln<<<dim3(M_ * B_), dim3(1024), 0, stream>>>(x, pW, pb, lg, lb, W1, b1, W2, b2, gamma, wf, Ssum, out);
    k_hist  <<<dim3(384),     dim3(256), 0, stream>>>(wf, cons, HT);
    k_pass  <<<dim3(512),     dim3(256), 0, stream>>>(wf, cons, gamma, mb, HT, Ssum, out);
}